// Round 1
// 686.760 us; speedup vs baseline: 1.1328x; 1.1328x over previous
//
#include <hip/hip_runtime.h>
#include <hip/hip_bf16.h>

// FastTSAGEConv: E=500000 edges, N=50000 nodes, F_IN=F_OUT=128.
// Device dtypes: float tensors = float32, index tensors = int32, output = float32.
// out[e,:] = dst_feat[e,:]@W_self + b_self + (segcumsum(src)[dst_max_eid[e],:]/(deg[e]+1))@W_neigh + b_neigh
// GEMM runs in bf16 MFMA (inputs converted on the fly); cumsum stored bf16 in ws.
//
// R1 change: seg_cumsum was latency-bound (15.6% HBM, VALU 16%): 2 serial
// binary searches (~34 dependent loads) + non-pipelined 10-iter accumulate
// loop. Replaced with (a) edge-parallel CSR offset build (node_start[N+1],
// stored in d_out's first 200KB, dead until gemm overwrites it), and
// (b) 2-deep register software pipeline in the cumsum loop.

#define FDIM 128
#define NNODES 50000

typedef __attribute__((ext_vector_type(4))) float f32x4;
typedef __attribute__((ext_vector_type(2))) float f32x2;
typedef __attribute__((ext_vector_type(8))) short bf16x8;

static __device__ __forceinline__ float bf2f(unsigned short u) {
  union { unsigned int i; float f; } v; v.i = ((unsigned int)u) << 16; return v.f;
}
static __device__ __forceinline__ unsigned short f2bf(float f) {
  union { float f; unsigned int i; } v; v.f = f;
  unsigned int x = v.i;
  return (unsigned short)((x + 0x7fffu + ((x >> 16) & 1u)) >> 16); // RNE
}

// ---------------------------------------------------------------------------
// Kernel 0: pack [W_self; W_neigh] (256x128 f32) into bf16 MFMA B-fragment
// order. Fragment (ks, n0, lane) = W_comb[ks*32 + (lane>>4)*8 + j][n0*16 + (lane&15)],
// j=0..7, stored contiguously at ((ks*8+n0)*64 + lane)*8 bf16. GEMM B-loads
// become one coalesced dwordx4 per fragment, L2-resident (64 KB total).
// ---------------------------------------------------------------------------
__global__ __launch_bounds__(256) void pack_w_kernel(
    const float* __restrict__ Wself,
    const float* __restrict__ Wneigh,
    unsigned short* __restrict__ Wp)
{
  int t = blockIdx.x * blockDim.x + threadIdx.x; // 0..4095
  if (t >= 8 * 8 * 64) return;
  int l  = t & 63;
  int n0 = (t >> 6) & 7;
  int ks = t >> 9;
  int n = n0 * 16 + (l & 15);
  int kbase = ks * 32 + ((l >> 4) * 8);
  unsigned short outv[8] __attribute__((aligned(16)));
#pragma unroll
  for (int j = 0; j < 8; ++j) {
    int k = kbase + j;
    float w = (k < FDIM) ? Wself[k * FDIM + n] : Wneigh[(k - FDIM) * FDIM + n];
    outv[j] = f2bf(w);
  }
  ((uint4*)Wp)[t] = *(const uint4*)outv;
}

// ---------------------------------------------------------------------------
// Kernel 1a: CSR offsets from sorted dst_ids. node_start[n] = first edge with
// dst >= n; node_start[NNODES] = E. Edge-parallel gap fill: each edge writes
// the (tiny) run of node ids between its predecessor's dst and its own dst.
// Replaces 2 per-wave binary searches (~34 dependent loads) in the cumsum.
// ---------------------------------------------------------------------------
__global__ __launch_bounds__(256) void seg_start_kernel(
    const int* __restrict__ dst_ids,
    int* __restrict__ node_start,
    int E, int nnodes)
{
  int e = blockIdx.x * blockDim.x + threadIdx.x;
  if (e >= E) return;
  int d = dst_ids[e];
  int dprev = (e == 0) ? -1 : dst_ids[e - 1];
  for (int n = dprev + 1; n <= d; ++n) node_start[n] = e;
  if (e == E - 1) {
    for (int n = d + 1; n <= nnodes; ++n) node_start[n] = E;
  }
}

// ---------------------------------------------------------------------------
// Kernel 1b: segmented inclusive cumsum of src_feat (f32) over dst segments.
// One wave per dst node, [start,end) from node_start. Lane i owns feature
// cols 2i,2i+1. 2-deep software pipeline: row j+2's load issues before row
// j's accumulate/store, keeping >=2 HBM loads in flight per wave.
// Stores bf16 cumsum rows (halves ws traffic).
// ---------------------------------------------------------------------------
__global__ __launch_bounds__(256) void seg_cumsum_kernel(
    const float* __restrict__ src,            // [E][128] f32
    const int* __restrict__ node_start,       // [NNODES+1] int32
    unsigned short* __restrict__ cs,          // [E][128] bf16 out
    int nnodes)
{
  int wave = (blockIdx.x * blockDim.x + threadIdx.x) >> 6;
  int lane = threadIdx.x & 63;
  if (wave >= nnodes) return;

  int s = node_start[wave];
  int e = node_start[wave + 1];
  if (s >= e) return;

  const float* sp = src + (size_t)s * FDIM + lane * 2;
  unsigned int* op = (unsigned int*)(cs + (size_t)s * FDIM + lane * 2);

  f32x2 v0 = *(const f32x2*)sp;
  f32x2 v1 = (s + 1 < e) ? *(const f32x2*)(sp + FDIM) : v0;
  float a0 = 0.f, a1 = 0.f;
  for (int j = s; j < e; ++j) {
    f32x2 vn = v1;
    if (j + 2 < e) vn = *(const f32x2*)(sp + (size_t)(j + 2 - s) * FDIM);
    a0 += v0.x;
    a1 += v0.y;
    unsigned int w = ((unsigned int)f2bf(a1) << 16) | (unsigned int)f2bf(a0);
    *op = w;
    op += FDIM / 2;   // one row = 128 bf16 = 64 uints
    v0 = v1;
    v1 = vn;
  }
}

// ---------------------------------------------------------------------------
// Kernel 2: out = [dst_feat | h_neigh] @ [W_self; W_neigh] + b_self + b_neigh
// Block = 256 thr = 4 waves; 16 edge-rows per wave (64/block).
// mfma_f32_16x16x32_bf16: A[m=lane&15][k=quad*8+j], B[k=quad*8+j][n=lane&15],
// D row=quad*4+reg, col=lane&15. K=256 => 8 k-steps; N=128 => 8 n-tiles.
// A-frags straight from global into regs; B-frags from packed Wp (L2). No LDS.
// ---------------------------------------------------------------------------
__global__ __launch_bounds__(256) void gemm_kernel(
    const float* __restrict__ dstf,            // [E][128] f32
    const unsigned short* __restrict__ cs,     // [E][128] bf16 (cumsum)
    const int* __restrict__ dst_max_eid,       // [E] int32
    const float* __restrict__ dst_deg,         // [E] f32 (integer-valued)
    const unsigned short* __restrict__ Wp,     // packed fragments, 32768 bf16
    const float* __restrict__ b_self,          // [128] f32
    const float* __restrict__ b_neigh,         // [128] f32
    float* __restrict__ out,                   // [E][128] f32
    int E)
{
  int lane = threadIdx.x & 63;
  int wave = threadIdx.x >> 6;
  int quad = lane >> 4;
  int lnib = lane & 15;
  int m0 = blockIdx.x * 64 + wave * 16;
  int row = m0 + lnib;
  int rclamp = (row < E) ? row : (E - 1);

  bf16x8 afrag[8];
  // self half: k in [0,128) — f32 rows converted to bf16
  const float* arow = dstf + (size_t)rclamp * FDIM + quad * 8;
#pragma unroll
  for (int ks = 0; ks < 4; ++ks) {
    f32x4 lo = *(const f32x4*)(arow + ks * 32);
    f32x4 hi = *(const f32x4*)(arow + ks * 32 + 4);
    bf16x8 a;
#pragma unroll
    for (int j = 0; j < 4; ++j) {
      a[j]     = (short)f2bf(lo[j]);
      a[4 + j] = (short)f2bf(hi[j]);
    }
    afrag[ks] = a;
  }

  // neigh half: gather bf16 cumsum row, scale by 1/(deg+1), k in [128,256)
  int eid = dst_max_eid[rclamp];
  float invc = 1.0f / (dst_deg[rclamp] + 1.0f);
  const unsigned short* nrow = cs + (size_t)eid * FDIM + quad * 8;
#pragma unroll
  for (int ks = 0; ks < 4; ++ks) {
    bf16x8 raw = *(const bf16x8*)(nrow + ks * 32);
    bf16x8 sc;
#pragma unroll
    for (int j = 0; j < 8; ++j)
      sc[j] = (short)f2bf(bf2f((unsigned short)raw[j]) * invc);
    afrag[4 + ks] = sc;
  }

  f32x4 acc[8];
#pragma unroll
  for (int n0 = 0; n0 < 8; ++n0) acc[n0] = (f32x4){0.f, 0.f, 0.f, 0.f};

  const bf16x8* wpv = (const bf16x8*)Wp;
#pragma unroll
  for (int ks = 0; ks < 8; ++ks) {
#pragma unroll
    for (int n0 = 0; n0 < 8; ++n0) {
      bf16x8 b = wpv[(ks * 8 + n0) * 64 + lane];
      acc[n0] = __builtin_amdgcn_mfma_f32_16x16x32_bf16(afrag[ks], b, acc[n0], 0, 0, 0);
    }
  }

  // epilogue: lane writes rows m0+quad*4+r, col n0*16+lnib (f32)
#pragma unroll
  for (int n0 = 0; n0 < 8; ++n0) {
    int n = n0 * 16 + lnib;
    float bias = b_self[n] + b_neigh[n];
#pragma unroll
    for (int r = 0; r < 4; ++r) {
      int orow = m0 + quad * 4 + r;
      if (orow < E)
        out[(size_t)orow * FDIM + n] = acc[n0][r] + bias;
    }
  }
}

extern "C" void kernel_launch(void* const* d_in, const int* in_sizes, int n_in,
                              void* d_out, int out_size, void* d_ws, size_t ws_size,
                              hipStream_t stream) {
  const float* src_feat    = (const float*)d_in[0];
  const float* dst_feat    = (const float*)d_in[1];
  const int*   dst_ids     = (const int*)d_in[2];
  const int*   dst_max_eid = (const int*)d_in[3];
  const float* dst_deg     = (const float*)d_in[4];
  const float* W_self      = (const float*)d_in[5];
  const float* b_self      = (const float*)d_in[6];
  const float* W_neigh     = (const float*)d_in[7];
  const float* b_neigh     = (const float*)d_in[8];

  int E = in_sizes[0] / FDIM;

  // ws layout: [0,64KB) packed bf16 W fragments; [64KB, 64KB + E*128*2) bf16 cumsum
  unsigned short* Wp = (unsigned short*)d_ws;
  unsigned short* cs = (unsigned short*)((char*)d_ws + 65536);

  // node_start[NNODES+1] lives in d_out's first 200KB — dead space until
  // gemm_kernel overwrites out (seg_start/seg_cumsum run strictly before).
  int* node_start = (int*)d_out;

  pack_w_kernel<<<16, 256, 0, stream>>>(W_self, W_neigh, Wp);

  int sblocks = (E + 255) / 256;
  seg_start_kernel<<<sblocks, 256, 0, stream>>>(dst_ids, node_start, E, NNODES);

  int nwaves_blocks = (NNODES * 64 + 255) / 256;
  seg_cumsum_kernel<<<nwaves_blocks, 256, 0, stream>>>(src_feat, node_start, cs, NNODES);

  int gblocks = (E + 63) / 64;
  gemm_kernel<<<gblocks, 256, 0, stream>>>(dst_feat, cs, dst_max_eid, dst_deg, Wp,
                                           b_self, b_neigh, (float*)d_out, E);
}

// Round 3
// 644.943 us; speedup vs baseline: 1.2063x; 1.0648x over previous
//
#include <hip/hip_runtime.h>
#include <hip/hip_bf16.h>

// FastTSAGEConv: E=500000 edges, N=50000 nodes, F_IN=F_OUT=128.
// Device dtypes: float tensors = float32, index tensors = int32, output = float32.
// out[e,:] = dst_feat[e,:]@W_self + b_self + (segcumsum(src)[dst_max_eid[e],:]/(deg[e]+1))@W_neigh + b_neigh
// GEMM runs in bf16 MFMA (inputs converted on the fly); cumsum stored bf16 in ws.
//
// R2 change: gemm was latency-bound (HBM 29%, MfmaUtil 7%, VALU 14%).
// (a) M_rep=2: 32 rows/wave, halves per-MFMA B traffic, doubles MFMA ILP.
// (b) n0-outer loop, per-n0 acc, explicit 2-deep B prefetch (bcur/bnext)
//     so the inner loop ticks at MFMA rate instead of L2 latency.
// (c) gather chain (eid -> cs row) issued first, self-loads + cvt overlap it.
// (d) seg_cumsum prefetch depth 2 -> 4 (named regs, uniform guards).
// R3: identical resubmit (R2 bench was lost to GPUAcquisitionTimeout).

#define FDIM 128
#define NNODES 50000

typedef __attribute__((ext_vector_type(4))) float f32x4;
typedef __attribute__((ext_vector_type(2))) float f32x2;
typedef __attribute__((ext_vector_type(8))) short bf16x8;

static __device__ __forceinline__ float bf2f(unsigned short u) {
  union { unsigned int i; float f; } v; v.i = ((unsigned int)u) << 16; return v.f;
}
static __device__ __forceinline__ unsigned short f2bf(float f) {
  union { float f; unsigned int i; } v; v.f = f;
  unsigned int x = v.i;
  return (unsigned short)((x + 0x7fffu + ((x >> 16) & 1u)) >> 16); // RNE
}

// ---------------------------------------------------------------------------
// Kernel 0: pack [W_self; W_neigh] (256x128 f32) into bf16 MFMA B-fragment
// order. Fragment (ks, n0, lane) = W_comb[ks*32 + (lane>>4)*8 + j][n0*16 + (lane&15)],
// j=0..7, stored contiguously at ((ks*8+n0)*64 + lane)*8 bf16. GEMM B-loads
// become one coalesced dwordx4 per fragment, L2-resident (64 KB total).
// ---------------------------------------------------------------------------
__global__ __launch_bounds__(256) void pack_w_kernel(
    const float* __restrict__ Wself,
    const float* __restrict__ Wneigh,
    unsigned short* __restrict__ Wp)
{
  int t = blockIdx.x * blockDim.x + threadIdx.x; // 0..4095
  if (t >= 8 * 8 * 64) return;
  int l  = t & 63;
  int n0 = (t >> 6) & 7;
  int ks = t >> 9;
  int n = n0 * 16 + (l & 15);
  int kbase = ks * 32 + ((l >> 4) * 8);
  unsigned short outv[8] __attribute__((aligned(16)));
#pragma unroll
  for (int j = 0; j < 8; ++j) {
    int k = kbase + j;
    float w = (k < FDIM) ? Wself[k * FDIM + n] : Wneigh[(k - FDIM) * FDIM + n];
    outv[j] = f2bf(w);
  }
  ((uint4*)Wp)[t] = *(const uint4*)outv;
}

// ---------------------------------------------------------------------------
// Kernel 1a: CSR offsets from sorted dst_ids. node_start[n] = first edge with
// dst >= n; node_start[NNODES] = E. Edge-parallel gap fill.
// ---------------------------------------------------------------------------
__global__ __launch_bounds__(256) void seg_start_kernel(
    const int* __restrict__ dst_ids,
    int* __restrict__ node_start,
    int E, int nnodes)
{
  int e = blockIdx.x * blockDim.x + threadIdx.x;
  if (e >= E) return;
  int d = dst_ids[e];
  int dprev = (e == 0) ? -1 : dst_ids[e - 1];
  for (int n = dprev + 1; n <= d; ++n) node_start[n] = e;
  if (e == E - 1) {
    for (int n = d + 1; n <= nnodes; ++n) node_start[n] = E;
  }
}

// ---------------------------------------------------------------------------
// Kernel 1b: segmented inclusive cumsum of src_feat (f32) over dst segments.
// One wave per dst node, [start,end) from node_start. Lane i owns feature
// cols 2i,2i+1. 4-deep register software pipeline (named regs v0..v3, rotated
// in a 4x-unrolled loop; k/n are wave-uniform so guards are scalar branches).
// Stores bf16 cumsum rows (halves ws traffic).
// ---------------------------------------------------------------------------
__global__ __launch_bounds__(256) void seg_cumsum_kernel(
    const float* __restrict__ src,            // [E][128] f32
    const int* __restrict__ node_start,       // [NNODES+1] int32
    unsigned short* __restrict__ cs,          // [E][128] bf16 out
    int nnodes)
{
  int wave = (blockIdx.x * blockDim.x + threadIdx.x) >> 6;
  int lane = threadIdx.x & 63;
  if (wave >= nnodes) return;

  int s = node_start[wave];
  int e = node_start[wave + 1];
  int n = e - s;
  if (n <= 0) return;

  const float* sp = src + (size_t)s * FDIM + lane * 2;
  unsigned int* op = (unsigned int*)(cs + (size_t)s * FDIM + lane * 2);

  // prologue: 4 prefetched rows (memory-safe: only rows < e touched)
  f32x2 z = {0.f, 0.f};
  f32x2 v0 = *(const f32x2*)sp;
  f32x2 v1 = (n > 1) ? *(const f32x2*)(sp + FDIM) : z;
  f32x2 v2 = (n > 2) ? *(const f32x2*)(sp + 2 * FDIM) : z;
  f32x2 v3 = (n > 3) ? *(const f32x2*)(sp + 3 * FDIM) : z;

  float a0 = 0.f, a1 = 0.f;
  int k = 0;
#define CS_STEP(V)                                                              \
  {                                                                             \
    a0 += V.x; a1 += V.y;                                                       \
    *op = ((unsigned int)f2bf(a1) << 16) | (unsigned int)f2bf(a0);              \
    op += FDIM / 2;                                                             \
    if (++k == n) break;                                                        \
    if (k + 3 < n) V = *(const f32x2*)(sp + (size_t)(k + 3) * FDIM);            \
  }
  while (true) {
    CS_STEP(v0)
    CS_STEP(v1)
    CS_STEP(v2)
    CS_STEP(v3)
  }
#undef CS_STEP
}

// ---------------------------------------------------------------------------
// Kernel 2: out = [dst_feat | h_neigh] @ [W_self; W_neigh] + b_self + b_neigh
// Block = 256 thr = 4 waves; 32 edge-rows per wave (2 m-tiles), 128/block.
// mfma_f32_16x16x32_bf16: A[m=lane&15][k=quad*8+j], B[k=quad*8+j][n=lane&15],
// D row=quad*4+reg, col=lane&15. K=256 => 8 k-steps; N=128 => 8 n-tiles.
// n0-outer loop: acc lives only per n0; B fragments 2-deep prefetched.
// Gather chain (eid -> cs row) issued first; self-loads/cvt overlap it.
// ---------------------------------------------------------------------------
__global__ __launch_bounds__(256) void gemm_kernel(
    const float* __restrict__ dstf,            // [E][128] f32
    const unsigned short* __restrict__ cs,     // [E][128] bf16 (cumsum)
    const int* __restrict__ dst_max_eid,       // [E] int32
    const float* __restrict__ dst_deg,         // [E] f32 (integer-valued)
    const unsigned short* __restrict__ Wp,     // packed fragments, 32768 bf16
    const float* __restrict__ b_self,          // [128] f32
    const float* __restrict__ b_neigh,         // [128] f32
    float* __restrict__ out,                   // [E][128] f32
    int E)
{
  int lane = threadIdx.x & 63;
  int wave = threadIdx.x >> 6;
  int quad = lane >> 4;
  int lnib = lane & 15;
  int m0 = blockIdx.x * 128 + wave * 32;

  int r0 = m0 + lnib;
  int r1 = m0 + 16 + lnib;
  int rc0 = (r0 < E) ? r0 : E - 1;
  int rc1 = (r1 < E) ? r1 : E - 1;

  // --- issue the long gather chain first ---
  int eid0 = dst_max_eid[rc0];
  int eid1 = dst_max_eid[rc1];
  float invc0 = 1.0f / (dst_deg[rc0] + 1.0f);
  float invc1 = 1.0f / (dst_deg[rc1] + 1.0f);

  const unsigned short* nrow0 = cs + (size_t)eid0 * FDIM + quad * 8;
  const unsigned short* nrow1 = cs + (size_t)eid1 * FDIM + quad * 8;
  bf16x8 raw0_0 = *(const bf16x8*)(nrow0);
  bf16x8 raw0_1 = *(const bf16x8*)(nrow0 + 32);
  bf16x8 raw0_2 = *(const bf16x8*)(nrow0 + 64);
  bf16x8 raw0_3 = *(const bf16x8*)(nrow0 + 96);
  bf16x8 raw1_0 = *(const bf16x8*)(nrow1);
  bf16x8 raw1_1 = *(const bf16x8*)(nrow1 + 32);
  bf16x8 raw1_2 = *(const bf16x8*)(nrow1 + 64);
  bf16x8 raw1_3 = *(const bf16x8*)(nrow1 + 96);

  // --- self-half loads (independent, overlap the gather latency) ---
  const float* arow0 = dstf + (size_t)rc0 * FDIM + quad * 8;
  const float* arow1 = dstf + (size_t)rc1 * FDIM + quad * 8;

  bf16x8 afrag0[8], afrag1[8];
#pragma unroll
  for (int ks = 0; ks < 4; ++ks) {
    f32x4 lo = *(const f32x4*)(arow0 + ks * 32);
    f32x4 hi = *(const f32x4*)(arow0 + ks * 32 + 4);
    bf16x8 a;
#pragma unroll
    for (int j = 0; j < 4; ++j) {
      a[j]     = (short)f2bf(lo[j]);
      a[4 + j] = (short)f2bf(hi[j]);
    }
    afrag0[ks] = a;
  }
#pragma unroll
  for (int ks = 0; ks < 4; ++ks) {
    f32x4 lo = *(const f32x4*)(arow1 + ks * 32);
    f32x4 hi = *(const f32x4*)(arow1 + ks * 32 + 4);
    bf16x8 a;
#pragma unroll
    for (int j = 0; j < 4; ++j) {
      a[j]     = (short)f2bf(lo[j]);
      a[4 + j] = (short)f2bf(hi[j]);
    }
    afrag1[ks] = a;
  }

  // --- bias preload (L2-hot after first blocks) ---
  float bias_r[8];
#pragma unroll
  for (int n0 = 0; n0 < 8; ++n0)
    bias_r[n0] = b_self[n0 * 16 + lnib] + b_neigh[n0 * 16 + lnib];

  // --- neigh-half conversion (gather results have arrived by now) ---
#pragma unroll
  for (int ks = 0; ks < 4; ++ks) {
    bf16x8 raw = (ks == 0) ? raw0_0 : (ks == 1) ? raw0_1 : (ks == 2) ? raw0_2 : raw0_3;
    bf16x8 sc;
#pragma unroll
    for (int j = 0; j < 8; ++j)
      sc[j] = (short)f2bf(bf2f((unsigned short)raw[j]) * invc0);
    afrag0[4 + ks] = sc;
  }
#pragma unroll
  for (int ks = 0; ks < 4; ++ks) {
    bf16x8 raw = (ks == 0) ? raw1_0 : (ks == 1) ? raw1_1 : (ks == 2) ? raw1_2 : raw1_3;
    bf16x8 sc;
#pragma unroll
    for (int j = 0; j < 8; ++j)
      sc[j] = (short)f2bf(bf2f((unsigned short)raw[j]) * invc1);
    afrag1[4 + ks] = sc;
  }

  // --- main loop: n0 outer, B fragments 2-deep prefetched ---
  const bf16x8* wpv = (const bf16x8*)Wp;
  bool full = (m0 + 32 <= E);

  bf16x8 bcur[8];
#pragma unroll
  for (int ks = 0; ks < 8; ++ks) bcur[ks] = wpv[ks * 512 + lane]; // n0 = 0

#pragma unroll
  for (int n0 = 0; n0 < 8; ++n0) {
    bf16x8 bnext[8];
    if (n0 < 7) {
#pragma unroll
      for (int ks = 0; ks < 8; ++ks)
        bnext[ks] = wpv[(ks * 8 + n0 + 1) * 64 + lane];
    }

    f32x4 a0 = (f32x4){0.f, 0.f, 0.f, 0.f};
    f32x4 a1 = (f32x4){0.f, 0.f, 0.f, 0.f};
#pragma unroll
    for (int ks = 0; ks < 8; ++ks) {
      a0 = __builtin_amdgcn_mfma_f32_16x16x32_bf16(afrag0[ks], bcur[ks], a0, 0, 0, 0);
      a1 = __builtin_amdgcn_mfma_f32_16x16x32_bf16(afrag1[ks], bcur[ks], a1, 0, 0, 0);
    }

    int n = n0 * 16 + lnib;
    float bias = bias_r[n0];
    if (full) {
#pragma unroll
      for (int r = 0; r < 4; ++r) {
        out[(size_t)(m0 + quad * 4 + r) * FDIM + n]      = a0[r] + bias;
        out[(size_t)(m0 + 16 + quad * 4 + r) * FDIM + n] = a1[r] + bias;
      }
    } else {
#pragma unroll
      for (int r = 0; r < 4; ++r) {
        int o0 = m0 + quad * 4 + r;
        int o1 = m0 + 16 + quad * 4 + r;
        if (o0 < E) out[(size_t)o0 * FDIM + n] = a0[r] + bias;
        if (o1 < E) out[(size_t)o1 * FDIM + n] = a1[r] + bias;
      }
    }

    if (n0 < 7) {
#pragma unroll
      for (int ks = 0; ks < 8; ++ks) bcur[ks] = bnext[ks];
    }
  }
}

extern "C" void kernel_launch(void* const* d_in, const int* in_sizes, int n_in,
                              void* d_out, int out_size, void* d_ws, size_t ws_size,
                              hipStream_t stream) {
  const float* src_feat    = (const float*)d_in[0];
  const float* dst_feat    = (const float*)d_in[1];
  const int*   dst_ids     = (const int*)d_in[2];
  const int*   dst_max_eid = (const int*)d_in[3];
  const float* dst_deg     = (const float*)d_in[4];
  const float* W_self      = (const float*)d_in[5];
  const float* b_self      = (const float*)d_in[6];
  const float* W_neigh     = (const float*)d_in[7];
  const float* b_neigh     = (const float*)d_in[8];

  int E = in_sizes[0] / FDIM;

  // ws layout: [0,64KB) packed bf16 W fragments; [64KB, 64KB + E*128*2) bf16 cumsum
  unsigned short* Wp = (unsigned short*)d_ws;
  unsigned short* cs = (unsigned short*)((char*)d_ws + 65536);

  // node_start[NNODES+1] lives in d_out's first 200KB — dead space until
  // gemm_kernel overwrites out (seg_start/seg_cumsum run strictly before).
  int* node_start = (int*)d_out;

  pack_w_kernel<<<16, 256, 0, stream>>>(W_self, W_neigh, Wp);

  int sblocks = (E + 255) / 256;
  seg_start_kernel<<<sblocks, 256, 0, stream>>>(dst_ids, node_start, E, NNODES);

  int nwaves_blocks = (NNODES * 64 + 255) / 256;
  seg_cumsum_kernel<<<nwaves_blocks, 256, 0, stream>>>(src_feat, node_start, cs, NNODES);

  int gblocks = (E + 127) / 128;
  gemm_kernel<<<gblocks, 256, 0, stream>>>(dst_feat, cs, dst_max_eid, dst_deg, Wp,
                                           b_self, b_neigh, (float*)d_out, E);
}